// Round 6
// baseline (208.973 us; speedup 1.0000x reference)
//
#include <hip/hip_runtime.h>
#include <math.h>

#define DM 192
#define DI 384
#define DS 16
#define DTR 12
#define BB 4
#define LL 3136
#define NTOK (BB*LL)
#define CHUNK 14
#define NCH (LL/CHUNK)
#define XDW 64   // padded x_dbl width (44 real cols: 12 dt, 16 B, 16 C)

typedef _Float16 half8 __attribute__((ext_vector_type(8)));
typedef float f32x4 __attribute__((ext_vector_type(4)));

__device__ __forceinline__ float warp_sum64(float v){
  #pragma unroll
  for (int m=32;m>=1;m>>=1) v += __shfl_xor(v, m, 64);
  return v;
}

// ---------------- K1: LayerNorm -> fp16 h (4 tokens/block, 1 wave each) ------
__global__ __launch_bounds__(256) void k_ln(const float* __restrict__ x,
    const float* __restrict__ w, const float* __restrict__ b, _Float16* __restrict__ h)
{
  int tok = blockIdx.x*4 + (threadIdx.x>>6);
  int lane = threadIdx.x & 63;
  const float* xr = x + (size_t)tok*DM;
  float v0 = xr[lane], v1 = xr[lane+64], v2 = xr[lane+128];
  float s = warp_sum64(v0+v1+v2);
  float mu = s * (1.0f/DM);
  float d0=v0-mu, d1=v1-mu, d2=v2-mu;
  float s2 = warp_sum64(d0*d0+d1*d1+d2*d2);
  float rs = rsqrtf(s2*(1.0f/DM) + 1e-5f);
  _Float16* hr = h + (size_t)tok*DM;
  hr[lane]     = (_Float16)(d0*rs*w[lane]     + b[lane]);
  hr[lane+64]  = (_Float16)(d1*rs*w[lane+64]  + b[lane+64]);
  hr[lane+128] = (_Float16)(d2*rs*w[lane+128] + b[lane+128]);
}

// ---------------- weight convert + transpose (+ optional col pad) ------------
__global__ __launch_bounds__(256) void k_w16t(const float* __restrict__ W,
  _Float16* __restrict__ Wt, int Kdim, int Ndim, int realN)
{
  int g = blockIdx.x*256 + threadIdx.x;
  if (g >= Kdim*Ndim) return;
  int k = g % Kdim, n = g / Kdim;
  Wt[g] = (n < realN) ? (_Float16)W[(size_t)k*realN + n] : (_Float16)0.f;
}

// ---------------- fp16 MFMA GEMM: C[M,N](f32) = A[M,K] @ Bt[N,K]^T -----------
__global__ __launch_bounds__(256) void k_hgemm(const _Float16* __restrict__ A,
  const _Float16* __restrict__ Bt, float* __restrict__ C, int M, int N, int K)
{
  __shared__ _Float16 As[64][40];
  __shared__ _Float16 Bs[64][40];
  int tid = threadIdx.x;
  int bm = blockIdx.y*64, bn = blockIdx.x*64;
  int wave = tid>>6, lane = tid&63;
  int wr = (wave>>1)*32, wc = (wave&1)*32;
  f32x4 acc00 = {0.f,0.f,0.f,0.f}, acc01 = {0.f,0.f,0.f,0.f};
  f32x4 acc10 = {0.f,0.f,0.f,0.f}, acc11 = {0.f,0.f,0.f,0.f};
  int sr = tid>>2;           // staging row 0..63
  int sc = (tid&3)*8;        // staging chunk (halves) 0,8,16,24
  int fr = lane&15;
  int fk = (lane>>4)*8;

  for (int k0=0; k0<K; k0+=32){
    *(float4*)&As[sr][sc] = *(const float4*)&A[(size_t)(bm+sr)*K + k0 + sc];
    *(float4*)&Bs[sr][sc] = *(const float4*)&Bt[(size_t)(bn+sr)*K + k0 + sc];
    __syncthreads();
    half8 a0 = *(const half8*)&As[wr + fr][fk];
    half8 a1 = *(const half8*)&As[wr + 16 + fr][fk];
    half8 b0 = *(const half8*)&Bs[wc + fr][fk];
    half8 b1 = *(const half8*)&Bs[wc + 16 + fr][fk];
    acc00 = __builtin_amdgcn_mfma_f32_16x16x32_f16(a0, b0, acc00, 0, 0, 0);
    acc01 = __builtin_amdgcn_mfma_f32_16x16x32_f16(a0, b1, acc01, 0, 0, 0);
    acc10 = __builtin_amdgcn_mfma_f32_16x16x32_f16(a1, b0, acc10, 0, 0, 0);
    acc11 = __builtin_amdgcn_mfma_f32_16x16x32_f16(a1, b1, acc11, 0, 0, 0);
    __syncthreads();
  }
  int rbase = (lane>>4)*4;
  #pragma unroll
  for (int q=0;q<4;++q){
    size_t row0 = (size_t)(bm + wr + rbase + q)*N + bn + wc;
    C[row0 + fr]           = acc00[q];
    C[row0 + 16 + fr]      = acc01[q];
    size_t row1 = (size_t)(bm + wr + 16 + rbase + q)*N + bn + wc;
    C[row1 + fr]           = acc10[q];
    C[row1 + 16 + fr]      = acc11[q];
  }
}

// ---------------- K3: depthwise causal conv (k=4) + bias + SiLU -> fp16 u ----
__global__ __launch_bounds__(256) void k_conv(const float* __restrict__ xz,
  const float* __restrict__ cw, const float* __restrict__ cb, _Float16* __restrict__ u)
{
  int g = blockIdx.x*256 + threadIdx.x;
  if (g >= NTOK*DI) return;
  int d = g % DI;
  int tok = g / DI;
  int l = tok % LL;
  float acc = cb[d];
  float w0=cw[d*4+0], w1=cw[d*4+1], w2=cw[d*4+2], w3=cw[d*4+3];
  const float* base = xz + (size_t)tok*768 + d;
  if (l>=3) acc += base[-3*768]*w0;
  if (l>=2) acc += base[-2*768]*w1;
  if (l>=1) acc += base[-1*768]*w2;
  acc += base[0]*w3;
  float sil = acc/(1.0f+__expf(-acc));
  u[g] = (_Float16)sil;
}

// ---------------- K5a: chunk-local scan. WG per (b,c), thread per d ----------
// delta recomputed in-register (softplus(dt.W+b)); B from LDS-staged xdbl.
__global__ __launch_bounds__(384) void k_scanA(
  const _Float16* __restrict__ u, const float* __restrict__ xdbl,
  const float* __restrict__ Alog, const float* __restrict__ dtw,
  const float* __restrict__ dtb,
  float* __restrict__ apb, float* __restrict__ heb)
{
  __shared__ float xd[CHUNK][XDW];
  int wg = blockIdx.x;           // b*NCH + c
  int b = wg / NCH, c = wg % NCH;
  int d = threadIdx.x;
  int tokbase = b*LL + c*CHUNK;
  for (int i = threadIdx.x; i < CHUNK*XDW; i += 384)
    ((float*)xd)[i] = xdbl[(size_t)(tokbase + i/XDW)*XDW + (i%XDW)];
  float A[DS];
  #pragma unroll
  for (int n=0;n<DS;++n) A[n] = -__expf(Alog[d*DS+n]);
  float W[DTR];
  #pragma unroll
  for (int r=0;r<DTR;++r) W[r] = dtw[r*DI + d];
  float bias = dtb[d];
  __syncthreads();
  float h[DS];
  #pragma unroll
  for (int n=0;n<DS;++n) h[n]=0.f;
  float sumdl = 0.f;
  for (int tt=0; tt<CHUNK; ++tt){
    size_t tok = (size_t)tokbase + tt;
    float acc = bias;
    #pragma unroll
    for (int r=0;r<DTR;++r) acc += xd[tt][r]*W[r];
    float dl = fmaxf(acc,0.f) + log1pf(__expf(-fabsf(acc)));
    sumdl += dl;
    float du = dl * (float)u[tok*DI + d];
    #pragma unroll
    for (int n=0;n<DS;++n){
      float dA = __expf(dl*A[n]);
      h[n] = dA*h[n] + du*xd[tt][DTR+n];
    }
  }
  size_t off = ((size_t)wg*DI + d)*DS;
  #pragma unroll
  for (int q=0;q<4;++q){
    f32x4 ap, he;
    #pragma unroll
    for (int j=0;j<4;++j){ ap[j] = __expf(A[q*4+j]*sumdl); he[j] = h[q*4+j]; }
    *(f32x4*)&apb[off+q*4] = ap;
    *(f32x4*)&heb[off+q*4] = he;
  }
}

// ---------------- K5b: cross-chunk scan; converts apb -> h_start in place ----
__global__ __launch_bounds__(256) void k_scanB(float* __restrict__ apb,
  const float* __restrict__ heb)
{
  int g = blockIdx.x*256+threadIdx.x;
  if (g >= BB*DI*4) return;
  int sg = g&3; int d = (g>>2)%DI; int b = (g>>2)/DI;
  float h0=0.f,h1=0.f,h2=0.f,h3=0.f;
  for (int c=0;c<NCH;++c){
    size_t off = ((size_t)((b*NCH+c)*DI)+d)*DS + sg*4;
    float4 ap = *(const float4*)&apb[off];
    float4 he = *(const float4*)&heb[off];
    float4 hs; hs.x=h0; hs.y=h1; hs.z=h2; hs.w=h3;
    *(float4*)&apb[off] = hs;
    h0 = ap.x*h0 + he.x;
    h1 = ap.y*h1 + he.y;
    h2 = ap.z*h2 + he.z;
    h3 = ap.w*h3 + he.w;
  }
}

// ---------------- K5c: re-scan with true h_start, fused epilogue -> fp16 -----
__global__ __launch_bounds__(384) void k_scanC(
  const _Float16* __restrict__ u, const float* __restrict__ xdbl,
  const float* __restrict__ Alog, const float* __restrict__ dtw,
  const float* __restrict__ dtb, const float* __restrict__ Dskip,
  const float* __restrict__ xz, const float* __restrict__ hstart,
  _Float16* __restrict__ outpre)
{
  __shared__ float xd[CHUNK][XDW];
  int wg = blockIdx.x;
  int b = wg / NCH, c = wg % NCH;
  int d = threadIdx.x;
  int tokbase = b*LL + c*CHUNK;
  for (int i = threadIdx.x; i < CHUNK*XDW; i += 384)
    ((float*)xd)[i] = xdbl[(size_t)(tokbase + i/XDW)*XDW + (i%XDW)];
  float A[DS];
  #pragma unroll
  for (int n=0;n<DS;++n) A[n] = -__expf(Alog[d*DS+n]);
  float W[DTR];
  #pragma unroll
  for (int r=0;r<DTR;++r) W[r] = dtw[r*DI + d];
  float bias = dtb[d];
  float dsk = Dskip[d];
  size_t off = ((size_t)wg*DI + d)*DS;
  float h[DS];
  #pragma unroll
  for (int q=0;q<4;++q){
    f32x4 hv = *(const f32x4*)&hstart[off+q*4];
    h[q*4+0]=hv[0]; h[q*4+1]=hv[1]; h[q*4+2]=hv[2]; h[q*4+3]=hv[3];
  }
  __syncthreads();
  for (int tt=0; tt<CHUNK; ++tt){
    size_t tok = (size_t)tokbase + tt;
    float acc = bias;
    #pragma unroll
    for (int r=0;r<DTR;++r) acc += xd[tt][r]*W[r];
    float dl = fmaxf(acc,0.f) + log1pf(__expf(-fabsf(acc)));
    float uu = (float)u[tok*DI + d];
    float du = dl*uu;
    float y = 0.f;
    #pragma unroll
    for (int n=0;n<DS;++n){
      float dA = __expf(dl*A[n]);
      h[n] = dA*h[n] + du*xd[tt][DTR+n];
      y += h[n]*xd[tt][DTR+DS+n];
    }
    y += uu*dsk;
    float z = xz[tok*768 + 384 + d];
    float sil = z/(1.0f+__expf(-z));
    outpre[tok*DI + d] = (_Float16)(y*sil);
  }
}

extern "C" void kernel_launch(void* const* d_in, const int* in_sizes, int n_in,
                              void* d_out, int out_size, void* d_ws, size_t ws_size,
                              hipStream_t stream) {
  const float* x         = (const float*)d_in[0];
  const float* ln_w      = (const float*)d_in[1];
  const float* ln_b      = (const float*)d_in[2];
  const float* in_proj_w = (const float*)d_in[3];
  const float* conv_w    = (const float*)d_in[4];
  const float* conv_b    = (const float*)d_in[5];
  const float* x_proj_w  = (const float*)d_in[6];
  const float* dt_proj_w = (const float*)d_in[7];
  const float* dt_proj_b = (const float*)d_in[8];
  const float* A_log     = (const float*)d_in[9];
  const float* D_skip    = (const float*)d_in[10];
  const float* out_proj_w= (const float*)d_in[11];
  float* out = (float*)d_out;

  float* ws = (float*)d_ws;
  size_t off = 0;
  float* xz    = ws + off; off += (size_t)NTOK*768;       // f32 38.5MB
  float* xdbl  = ws + off; off += (size_t)NTOK*XDW;       // f32 3.2MB
  float* apb   = ws + off; off += (size_t)BB*NCH*DI*DS;   // f32 22MB (-> h_start)
  float* heb   = ws + off; off += (size_t)BB*NCH*DI*DS;   // f32 22MB
  _Float16* h16   = (_Float16*)(ws + off); off += (size_t)NTOK*DM/2;
  _Float16* u16   = (_Float16*)(ws + off); off += (size_t)NTOK*DI/2;
  _Float16* op16  = (_Float16*)(ws + off); off += (size_t)NTOK*DI/2;
  _Float16* wtin  = (_Float16*)(ws + off); off += (size_t)768*DM/2;
  _Float16* wtxp  = (_Float16*)(ws + off); off += (size_t)XDW*DI/2;
  _Float16* wtout = (_Float16*)(ws + off); off += (size_t)DM*DI/2;

  // 0. weight convert+transpose (f16, Wt[N][K])
  k_w16t<<<(768*DM+255)/256, 256, 0, stream>>>(in_proj_w,  wtin,  DM, 768, 768);
  k_w16t<<<(XDW*DI+255)/256, 256, 0, stream>>>(x_proj_w,   wtxp,  DI, XDW, DTR+2*DS);
  k_w16t<<<(DM*DI+255)/256, 256, 0, stream>>>(out_proj_w, wtout, DI, DM,  DM);
  // 1. LayerNorm -> f16
  k_ln<<<NTOK/4, 256, 0, stream>>>(x, ln_w, ln_b, h16);
  // 2. in_proj MFMA GEMM: [12544,192] @ [192,768] -> f32 xz
  {
    dim3 g(768/64, NTOK/64);
    k_hgemm<<<g, 256, 0, stream>>>(h16, wtin, xz, NTOK, 768, DM);
  }
  // 3. conv + SiLU -> f16 u
  k_conv<<<(NTOK*DI)/256, 256, 0, stream>>>(xz, conv_w, conv_b, u16);
  // 4. x_proj MFMA GEMM: [12544,384] @ [384,64] -> f32 xdbl
  {
    dim3 g(XDW/64, NTOK/64);
    k_hgemm<<<g, 256, 0, stream>>>(u16, wtxp, xdbl, NTOK, XDW, DI);
  }
  // 5. chunked scan (WG per (b,c); delta fused in-register)
  k_scanA<<<BB*NCH, 384, 0, stream>>>(u16, xdbl, A_log, dt_proj_w, dt_proj_b,
                                      apb, heb);
  k_scanB<<<(BB*DI*4+255)/256, 256, 0, stream>>>(apb, heb);
  k_scanC<<<BB*NCH, 384, 0, stream>>>(u16, xdbl, A_log, dt_proj_w, dt_proj_b,
                                      D_skip, xz, apb, op16);
  // 6. out_proj MFMA GEMM: [12544,384] @ [384,192] -> d_out (f32)
  {
    dim3 g(DM/64, NTOK/64);
    k_hgemm<<<g, 256, 0, stream>>>(op16, wtout, out, NTOK, DM, DI);
  }
}

// Round 7
// 207.890 us; speedup vs baseline: 1.0052x; 1.0052x over previous
//
#include <hip/hip_runtime.h>
#include <math.h>

#define DM 192
#define DI 384
#define DS 16
#define DTR 12
#define BB 4
#define LL 3136
#define NTOK (BB*LL)
#define CHUNK 28
#define NCH (LL/CHUNK)
#define XDW 64   // padded x_dbl width (44 real cols: 12 dt, 16 B, 16 C)

typedef _Float16 half8 __attribute__((ext_vector_type(8)));
typedef float f32x4 __attribute__((ext_vector_type(4)));

__device__ __forceinline__ float warp_sum64(float v){
  #pragma unroll
  for (int m=32;m>=1;m>>=1) v += __shfl_xor(v, m, 64);
  return v;
}

// ---------------- K1: LayerNorm -> fp16 h (4 tokens/block) -------------------
__global__ __launch_bounds__(256) void k_ln(const float* __restrict__ x,
    const float* __restrict__ w, const float* __restrict__ b, _Float16* __restrict__ h)
{
  int tok = blockIdx.x*4 + (threadIdx.x>>6);
  int lane = threadIdx.x & 63;
  const float* xr = x + (size_t)tok*DM;
  float v0 = xr[lane], v1 = xr[lane+64], v2 = xr[lane+128];
  float s = warp_sum64(v0+v1+v2);
  float mu = s * (1.0f/DM);
  float d0=v0-mu, d1=v1-mu, d2=v2-mu;
  float s2 = warp_sum64(d0*d0+d1*d1+d2*d2);
  float rs = rsqrtf(s2*(1.0f/DM) + 1e-5f);
  _Float16* hr = h + (size_t)tok*DM;
  hr[lane]     = (_Float16)(d0*rs*w[lane]     + b[lane]);
  hr[lane+64]  = (_Float16)(d1*rs*w[lane+64]  + b[lane+64]);
  hr[lane+128] = (_Float16)(d2*rs*w[lane+128] + b[lane+128]);
}

// ---------------- weight convert + transpose (+ optional col pad) ------------
__global__ __launch_bounds__(256) void k_w16t(const float* __restrict__ W,
  _Float16* __restrict__ Wt, int Kdim, int Ndim, int realN)
{
  int g = blockIdx.x*256 + threadIdx.x;
  if (g >= Kdim*Ndim) return;
  int k = g % Kdim, n = g / Kdim;
  Wt[g] = (n < realN) ? (_Float16)W[(size_t)k*realN + n] : (_Float16)0.f;
}

// ---------------- Aneg = -exp(A_log), precomputed once -----------------------
__global__ __launch_bounds__(256) void k_prepA(const float* __restrict__ Alog,
  float* __restrict__ Aneg)
{
  int g = blockIdx.x*256 + threadIdx.x;
  if (g >= DI*DS) return;
  Aneg[g] = -__expf(Alog[g]);
}

// ---------------- fp16 MFMA GEMM: C[M,N](f32) = A[M,K] @ Bt[N,K]^T -----------
__global__ __launch_bounds__(256) void k_hgemm(const _Float16* __restrict__ A,
  const _Float16* __restrict__ Bt, float* __restrict__ C, int M, int N, int K)
{
  __shared__ _Float16 As[64][40];
  __shared__ _Float16 Bs[64][40];
  int tid = threadIdx.x;
  int bm = blockIdx.y*64, bn = blockIdx.x*64;
  int wave = tid>>6, lane = tid&63;
  int wr = (wave>>1)*32, wc = (wave&1)*32;
  f32x4 acc00 = {0.f,0.f,0.f,0.f}, acc01 = {0.f,0.f,0.f,0.f};
  f32x4 acc10 = {0.f,0.f,0.f,0.f}, acc11 = {0.f,0.f,0.f,0.f};
  int sr = tid>>2;
  int sc = (tid&3)*8;
  int fr = lane&15;
  int fk = (lane>>4)*8;

  for (int k0=0; k0<K; k0+=32){
    *(float4*)&As[sr][sc] = *(const float4*)&A[(size_t)(bm+sr)*K + k0 + sc];
    *(float4*)&Bs[sr][sc] = *(const float4*)&Bt[(size_t)(bn+sr)*K + k0 + sc];
    __syncthreads();
    half8 a0 = *(const half8*)&As[wr + fr][fk];
    half8 a1 = *(const half8*)&As[wr + 16 + fr][fk];
    half8 b0 = *(const half8*)&Bs[wc + fr][fk];
    half8 b1 = *(const half8*)&Bs[wc + 16 + fr][fk];
    acc00 = __builtin_amdgcn_mfma_f32_16x16x32_f16(a0, b0, acc00, 0, 0, 0);
    acc01 = __builtin_amdgcn_mfma_f32_16x16x32_f16(a0, b1, acc01, 0, 0, 0);
    acc10 = __builtin_amdgcn_mfma_f32_16x16x32_f16(a1, b0, acc10, 0, 0, 0);
    acc11 = __builtin_amdgcn_mfma_f32_16x16x32_f16(a1, b1, acc11, 0, 0, 0);
    __syncthreads();
  }
  int rbase = (lane>>4)*4;
  #pragma unroll
  for (int q=0;q<4;++q){
    size_t row0 = (size_t)(bm + wr + rbase + q)*N + bn + wc;
    C[row0 + fr]           = acc00[q];
    C[row0 + 16 + fr]      = acc01[q];
    size_t row1 = (size_t)(bm + wr + 16 + rbase + q)*N + bn + wc;
    C[row1 + fr]           = acc10[q];
    C[row1 + 16 + fr]      = acc11[q];
  }
}

// ---------------- K3: depthwise causal conv (k=4) + bias + SiLU -> fp16 u ----
__global__ __launch_bounds__(256) void k_conv(const float* __restrict__ xz,
  const float* __restrict__ cw, const float* __restrict__ cb, _Float16* __restrict__ u)
{
  int g = blockIdx.x*256 + threadIdx.x;
  if (g >= NTOK*DI) return;
  int d = g % DI;
  int tok = g / DI;
  int l = tok % LL;
  float acc = cb[d];
  float w0=cw[d*4+0], w1=cw[d*4+1], w2=cw[d*4+2], w3=cw[d*4+3];
  const float* base = xz + (size_t)tok*768 + d;
  if (l>=3) acc += base[-3*768]*w0;
  if (l>=2) acc += base[-2*768]*w1;
  if (l>=1) acc += base[-1*768]*w2;
  acc += base[0]*w3;
  float sil = acc/(1.0f+__expf(-acc));
  u[g] = (_Float16)sil;
}

// ---------------- K4b: delta = softplus(dt @ dt_proj_w + b) ------------------
__global__ __launch_bounds__(256) void k_delta(const float* __restrict__ xdbl,
  const float* __restrict__ W, const float* __restrict__ bias, float* __restrict__ delta)
{
  int g = blockIdx.x*256+threadIdx.x;
  if (g >= NTOK*DI) return;
  int d = g % DI; int tok = g / DI;
  float acc = bias[d];
  const float* dtr = xdbl + (size_t)tok*XDW;
  #pragma unroll
  for (int r=0;r<DTR;++r) acc += dtr[r]*W[r*DI+d];
  float sp = fmaxf(acc,0.f) + log1pf(__expf(-fabsf(acc)));
  delta[g] = sp;
}

// ---------------- K5a: single sequential pass. quad per (b,c,d) --------------
// Emits: per-token y_local (into xz u-slot, incl. u*Dskip), per-token cumdl,
// and per-chunk summaries apb=exp(A*sumdl), heb=h_local_end.
__global__ __launch_bounds__(256) void k_scanA(const float* __restrict__ delta,
  const _Float16* __restrict__ u, const float* __restrict__ xdbl,
  const float* __restrict__ Aneg, const float* __restrict__ Dskip,
  float* __restrict__ cumdl, float* __restrict__ ylocal /* xz base: stride 768 */,
  float* __restrict__ apb, float* __restrict__ heb)
{
  int g = blockIdx.x*256+threadIdx.x;
  if (g >= BB*NCH*DI*4) return;
  int sg = g & 3;
  int d  = (g>>2) % DI;
  int c  = ((g>>2)/DI) % NCH;
  int b  = g/(4*DI*NCH);
  f32x4 A4 = *(const f32x4*)&Aneg[d*DS + sg*4];
  float A[4] = {A4[0],A4[1],A4[2],A4[3]};
  float h[4] = {0.f,0.f,0.f,0.f};
  float cum = 0.f;
  float dsk = Dskip[d];
  int t0 = c*CHUNK;
  #pragma unroll 4
  for (int t=t0; t<t0+CHUNK; ++t){
    size_t tok = (size_t)b*LL + t;
    float dl = delta[tok*DI + d];
    cum += dl;
    float uu = (float)u[tok*DI + d];
    float du = dl*uu;
    float4 bc4 = *(const float4*)&xdbl[tok*XDW + DTR + sg*4];
    float4 cc4 = *(const float4*)&xdbl[tok*XDW + DTR + DS + sg*4];
    float y;
    {
      float dA0=__expf(dl*A[0]); h[0]=dA0*h[0]+du*bc4.x; y  = h[0]*cc4.x;
      float dA1=__expf(dl*A[1]); h[1]=dA1*h[1]+du*bc4.y; y += h[1]*cc4.y;
      float dA2=__expf(dl*A[2]); h[2]=dA2*h[2]+du*bc4.z; y += h[2]*cc4.z;
      float dA3=__expf(dl*A[3]); h[3]=dA3*h[3]+du*bc4.w; y += h[3]*cc4.w;
    }
    y += __shfl_xor(y, 1, 64);
    y += __shfl_xor(y, 2, 64);
    if (sg == 0){
      ylocal[tok*768 + d] = y + uu*dsk;
      cumdl[tok*DI + d] = cum;
    }
  }
  size_t off = ((size_t)((b*NCH + c)*DI) + d)*DS + sg*4;
  f32x4 ap, he;
  #pragma unroll
  for (int j=0;j<4;++j){ ap[j] = __expf(A[j]*cum); he[j] = h[j]; }
  *(f32x4*)&apb[off] = ap;
  *(f32x4*)&heb[off] = he;
}

// ---------------- K5b: cross-chunk scan; converts apb -> h_start in place ----
__global__ __launch_bounds__(256) void k_scanB(float* __restrict__ apb,
  const float* __restrict__ heb)
{
  int g = blockIdx.x*256+threadIdx.x;
  if (g >= BB*DI*4) return;
  int sg = g&3; int d = (g>>2)%DI; int b = (g>>2)/DI;
  float h0=0.f,h1=0.f,h2=0.f,h3=0.f;
  for (int c=0;c<NCH;++c){
    size_t off = ((size_t)((b*NCH+c)*DI)+d)*DS + sg*4;
    float4 ap = *(const float4*)&apb[off];
    float4 he = *(const float4*)&heb[off];
    float4 hs; hs.x=h0; hs.y=h1; hs.z=h2; hs.w=h3;
    *(float4*)&apb[off] = hs;
    h0 = ap.x*h0 + he.x;
    h1 = ap.y*h1 + he.y;
    h2 = ap.z*h2 + he.z;
    h3 = ap.w*h3 + he.w;
  }
}

// ---------------- K5c: parallel fixup + epilogue -> fp16 ---------------------
// y = y_local + sum_n exp(A[n]*cumdl)*h_start[n]*C[n];  out = y*silu(z)
__global__ __launch_bounds__(256) void k_fixup(const float* __restrict__ cumdl,
  const float* __restrict__ xz, const float* __restrict__ xdbl,
  const float* __restrict__ Aneg, const float* __restrict__ hstart,
  _Float16* __restrict__ outpre)
{
  int g = blockIdx.x*256+threadIdx.x;
  if (g >= NTOK*DI) return;
  int d = g % DI;
  size_t tok = g / DI;
  int l = (int)(tok % LL);
  int b = (int)(tok / LL);
  int c = l / CHUNK;
  float cd = cumdl[g];
  size_t hoff = ((size_t)((b*NCH + c)*DI) + d)*DS;
  const float* Cc = &xdbl[tok*XDW + DTR + DS];
  const float* An = &Aneg[d*DS];
  float corr = 0.f;
  #pragma unroll
  for (int q=0;q<4;++q){
    f32x4 a4 = *(const f32x4*)&An[q*4];
    f32x4 hs = *(const f32x4*)&hstart[hoff + q*4];
    f32x4 c4 = *(const f32x4*)&Cc[q*4];
    corr += __expf(a4[0]*cd)*hs[0]*c4[0];
    corr += __expf(a4[1]*cd)*hs[1]*c4[1];
    corr += __expf(a4[2]*cd)*hs[2]*c4[2];
    corr += __expf(a4[3]*cd)*hs[3]*c4[3];
  }
  float y = xz[tok*768 + d] + corr;     // y_local stored in xz u-slot
  float z = xz[tok*768 + 384 + d];
  float sil = z/(1.0f+__expf(-z));
  outpre[g] = (_Float16)(y*sil);
}

extern "C" void kernel_launch(void* const* d_in, const int* in_sizes, int n_in,
                              void* d_out, int out_size, void* d_ws, size_t ws_size,
                              hipStream_t stream) {
  const float* x         = (const float*)d_in[0];
  const float* ln_w      = (const float*)d_in[1];
  const float* ln_b      = (const float*)d_in[2];
  const float* in_proj_w = (const float*)d_in[3];
  const float* conv_w    = (const float*)d_in[4];
  const float* conv_b    = (const float*)d_in[5];
  const float* x_proj_w  = (const float*)d_in[6];
  const float* dt_proj_w = (const float*)d_in[7];
  const float* dt_proj_b = (const float*)d_in[8];
  const float* A_log     = (const float*)d_in[9];
  const float* D_skip    = (const float*)d_in[10];
  const float* out_proj_w= (const float*)d_in[11];
  float* out = (float*)d_out;

  float* ws = (float*)d_ws;
  size_t off = 0;
  float* xz    = ws + off; off += (size_t)NTOK*768;       // f32 38.5MB (u-slot becomes y_local)
  float* delta = ws + off; off += (size_t)NTOK*DI;        // f32 19.3MB
  float* cumdl = ws + off; off += (size_t)NTOK*DI;        // f32 19.3MB
  float* xdbl  = ws + off; off += (size_t)NTOK*XDW;       // f32 3.2MB
  float* apb   = ws + off; off += (size_t)BB*NCH*DI*DS;   // f32 11MB (-> h_start)
  float* heb   = ws + off; off += (size_t)BB*NCH*DI*DS;   // f32 11MB
  float* aneg  = ws + off; off += (size_t)DI*DS;          // 24KB
  _Float16* h16   = (_Float16*)(ws + off); off += (size_t)NTOK*DM/2;
  _Float16* u16   = (_Float16*)(ws + off); off += (size_t)NTOK*DI/2;
  _Float16* op16  = (_Float16*)(ws + off); off += (size_t)NTOK*DI/2;
  _Float16* wtin  = (_Float16*)(ws + off); off += (size_t)768*DM/2;
  _Float16* wtxp  = (_Float16*)(ws + off); off += (size_t)XDW*DI/2;
  _Float16* wtout = (_Float16*)(ws + off); off += (size_t)DM*DI/2;

  // 0. weight convert+transpose (f16, Wt[N][K]) + Aneg
  k_w16t<<<(768*DM+255)/256, 256, 0, stream>>>(in_proj_w,  wtin,  DM, 768, 768);
  k_w16t<<<(XDW*DI+255)/256, 256, 0, stream>>>(x_proj_w,   wtxp,  DI, XDW, DTR+2*DS);
  k_w16t<<<(DM*DI+255)/256, 256, 0, stream>>>(out_proj_w, wtout, DI, DM,  DM);
  k_prepA<<<(DI*DS+255)/256, 256, 0, stream>>>(A_log, aneg);
  // 1. LayerNorm -> f16
  k_ln<<<NTOK/4, 256, 0, stream>>>(x, ln_w, ln_b, h16);
  // 2. in_proj MFMA GEMM: [12544,192] @ [192,768] -> f32 xz
  {
    dim3 g(768/64, NTOK/64);
    k_hgemm<<<g, 256, 0, stream>>>(h16, wtin, xz, NTOK, 768, DM);
  }
  // 3. conv + SiLU -> f16 u
  k_conv<<<(NTOK*DI)/256, 256, 0, stream>>>(xz, conv_w, conv_b, u16);
  // 4. x_proj MFMA GEMM: [12544,384] @ [384,64] -> f32 xdbl
  {
    dim3 g(XDW/64, NTOK/64);
    k_hgemm<<<g, 256, 0, stream>>>(u16, wtxp, xdbl, NTOK, XDW, DI);
  }
  // 4b. dt_proj + softplus
  k_delta<<<(NTOK*DI)/256, 256, 0, stream>>>(xdbl, dt_proj_w, dt_proj_b, delta);
  // 5. single sequential pass + tiny cross-chunk scan + parallel fixup
  k_scanA<<<(BB*NCH*DI*4)/256, 256, 0, stream>>>(delta, u16, xdbl, aneg, D_skip,
                                                 cumdl, xz, apb, heb);
  k_scanB<<<(BB*DI*4+255)/256, 256, 0, stream>>>(apb, heb);
  k_fixup<<<(NTOK*DI)/256, 256, 0, stream>>>(cumdl, xz, xdbl, aneg, apb, op16);
  // 6. out_proj MFMA GEMM: [12544,384] @ [384,192] -> d_out (f32)
  {
    dim3 g(DM/64, NTOK/64);
    k_hgemm<<<g, 256, 0, stream>>>(op16, wtout, out, NTOK, DM, DI);
  }
}